// Round 15
// baseline (118.039 us; speedup 1.0000x reference)
//
#include <hip/hip_runtime.h>
#include <math.h>
#include <stdint.h>

#define N_STFT 1025
#define N_MELS 128
#define BATCH 4
#define TIME 1024
#define MAX_ITER 20

typedef unsigned int u32;
typedef unsigned long long u64;
typedef float f32x2 __attribute__((ext_vector_type(2)));

// Packed f32 math (CDNA VOP3P): 2 lanes of f32 per instruction.
__device__ __forceinline__ f32x2 pk_fma(f32x2 a, f32x2 b, f32x2 c) {
  f32x2 d;
  asm("v_pk_fma_f32 %0, %1, %2, %3" : "=v"(d) : "v"(a), "v"(b), "v"(c));
  return d;
}
__device__ __forceinline__ f32x2 pk_mul(f32x2 a, f32x2 b) {
  f32x2 d;
  asm("v_pk_mul_f32 %0, %1, %2" : "=v"(d) : "v"(a), "v"(b));
  return d;
}

// r23 = r18 champion (49.2us) + two WORK cuts, skeleton untouched.
// Ledger: r22 proved __float2int_rn is 1 instr (RNE default mode) and that
// phase-stagger only adds stall; all overlap schemes failed -> cut work.
// (1) cc[16] ELIMINATED: P initialized to -round(mel[m]*2^24) instead of 0
//     (the zero-write becomes an init-write of a cached u64 pair, same DS
//     cost). Post-forward P IS diff*2^24; g = (p0*rw0s + p1*rw1s)*2^-48.
//     -16 live VGPRs (+2 init regs) — relieves the 96-live vs 80-alloc
//     squeeze (probable L2-scratch spills behind the stubborn 50% VALUBusy).
// (2) backward math PACKED: v_pk_fma/mul on k-pairs: 9 instr/pair vs 16
//     (cvts+maxes stay scalar) -> ~-56 VALU instr/iter (~15% of issue).
// Forward chain/predicated atomics/read2 backward/wave-private P/grid/
// swizzle/epilogue/host-table: exactly r18.
__global__ __launch_bounds__(256)
__attribute__((amdgpu_waves_per_eu(2, 4))) void imel_main(
    const float* __restrict__ melspec, const float* __restrict__ spec_init,
    const int* __restrict__ m0f, const float* __restrict__ w0a,
    const float* __restrict__ w1a, float* __restrict__ out) {
  __shared__ u32   s_P[4][N_MELS];   // per-wave private P row (i32 fixed pt)
  __shared__ float s_mel[4][N_MELS]; // staged mel columns (prologue only)
  __shared__ float s_out[4][1060];   // swizzle-padded: idx = f + (f>>5)

  const int tid = threadIdx.x;
  const int w   = tid >> 6;        // wave 0..3 -> row t0+w
  const int l   = tid & 63;
  // XCD swizzle for grid 1024: XCD x covers flats [x*128, x*128+128) -> L2
  // locality for melspec slice + adjacent output granules merge in L2.
  const int flat = (blockIdx.x & 7) * 128 + (blockIdx.x >> 3);
  const int b   = flat >> 8;          // 256 flats per batch
  const int t0  = (flat & 255) << 2;  // block covers t0..t0+3
  const int tA  = t0 + w;

  // ---- stage mel columns: s_mel[r][m] = mel[b][m][t0+r] ----
  for (int i = tid; i < 4 * N_MELS; i += 256) {
    const int m = i >> 2, r = i & 3;
    s_mel[r][m] = melspec[((size_t)b * N_MELS + m) * TIME + t0 + r];
  }
  __syncthreads();

  const float SCALE = 16777216.0f;                 // 2^24 fixed point
  const float INV48 = 3.5527136788005009e-15f;     // 2^-48 (rw 2^24-scaled)
  const float LRI   = 0.3f * (2.0f / (BATCH * TIME)); // 1.46484375e-4f

  // per-lane static structure, f = 16*l + k, packed in pairs (k=2j, 2j+1)
  f32x2 rsp[8], rbp[8], rw0p[8], rw1p[8];
  int rm[16];

  const float* srow = spec_init + (size_t)(b * TIME + tA) * N_STFT;
  const float* melW = &s_mel[w][0];
#pragma unroll
  for (int k = 0; k < 16; ++k) {
    const int f = (l << 4) + k;
    const float s  = srow[f];
    const int   m  = m0f[f];
    rm[k] = m;
    const float w0 = w0a[f] * SCALE;
    const float w1 = w1a[f] * SCALE;
    if (k & 1) {
      rsp[k >> 1].y = s;  rw0p[k >> 1].y = w0;
      rw1p[k >> 1].y = w1; rbp[k >> 1].y = 0.f;
    } else {
      rsp[k >> 1].x = s;  rw0p[k >> 1].x = w0;
      rw1p[k >> 1].x = w1; rbp[k >> 1].x = 0.f;
    }
  }
  const float rt = (l == 63) ? srow[1024] : 0.f;

  // P init value: bins 2l, 2l+1 get -round(mel*2^24)  (mel folded into P;
  // forward adds positive contributions; result = diff*2^24, signed)
  const int mi0 = __float2int_rn(melW[2 * l] * SCALE);
  const int mi1 = __float2int_rn(melW[2 * l + 1] * SCALE);
  const u64 pinit = (u64)(u32)(-mi0) | ((u64)(u32)(-mi1) << 32);

  u32* __restrict__ Pw = &s_P[w][0];
  ((u64*)Pw)[l] = pinit;             // one ds_write_b64 inits 2 bins/lane
  // wave-private P: no block barrier anywhere in the hot loop

#define RS_(k) ((k & 1) ? rsp[k >> 1].y : rsp[k >> 1].x)
#define RW0_(k) ((k & 1) ? rw0p[k >> 1].y : rw0p[k >> 1].x)
#define RW1_(k) ((k & 1) ? rw1p[k >> 1].y : rw1p[k >> 1].x)

  const f32x2 PK_NINE = {0.9f, 0.9f};
  const f32x2 PK_INV48 = {INV48, INV48};
  const f32x2 PK_NLRI = {-LRI, -LRI};

  for (int it = 0; it < MAX_ITER; ++it) {
    // ---- forward: run-compacted scatter (native ds_add_u32) ----
    {
      float a0 = RS_(0) * RW0_(0), a1 = RS_(0) * RW1_(0);
#pragma unroll
      for (int k = 1; k < 16; ++k) {
        const bool adv = (rm[k] != rm[k - 1]);  // m0 monotone, step <= 1/bin
        if (adv) atomicAdd(&Pw[rm[k - 1]], (u32)__float2int_rn(a0));
        const float n0 = (adv ? a1 : a0) + RS_(k) * RW0_(k);
        a1 = (adv ? 0.f : a1) + RS_(k) * RW1_(k);
        a0 = n0;
      }
      atomicAdd(&Pw[rm[15]],     (u32)__float2int_rn(a0));
      atomicAdd(&Pw[rm[15] + 1], (u32)__float2int_rn(a1));
    }
    __builtin_amdgcn_wave_barrier();   // scheduling fence only
    // ---- backward: unpredicated ds_read2_b32 pairs (r20 lesson: keep
    //      independent), packed momentum/update math ----
#pragma unroll
    for (int j = 0; j < 8; ++j) {
      const u32 qa0 = Pw[rm[2 * j]];          // read2 pair
      const u32 qa1 = Pw[rm[2 * j] + 1];
      const u32 qb0 = Pw[rm[2 * j + 1]];      // read2 pair
      const u32 qb1 = Pw[rm[2 * j + 1] + 1];
      f32x2 p0, p1;
      p0.x = (float)(int)qa0; p0.y = (float)(int)qb0;
      p1.x = (float)(int)qa1; p1.y = (float)(int)qb1;
      const f32x2 t = pk_fma(p0, rw0p[j], pk_mul(p1, rw1p[j]));
      const f32x2 g = pk_mul(t, PK_INV48);    // diff-grad (mel inside P)
      rbp[j] = pk_fma(PK_NINE, rbp[j], g);
      const f32x2 u = pk_fma(PK_NLRI, rbp[j], rsp[j]);
      rsp[j].x = fmaxf(u.x, 0.f);
      rsp[j].y = fmaxf(u.y, 0.f);
    }
    __builtin_amdgcn_wave_barrier();
    // ---- re-init P (-mel*2^24) for next iteration (same-wave order) ----
    ((u64*)Pw)[l] = pinit;
    __builtin_amdgcn_wave_barrier();
  }

  // ---- epilogue: transpose (f-major regs) -> (B, F, T) via swizzled LDS ----
#pragma unroll
  for (int k = 0; k < 16; ++k) {
    const int f = (l << 4) + k;
    s_out[w][f + (f >> 5)] = RS_(k);
  }
  if (l == 63) s_out[w][1056] = rt;    // f=1024 -> 1024 + (1024>>5)
  __syncthreads();

  const int tl = tid & 3;    // t offset within the block's 4 rows
  const int fg = tid >> 2;   // 64 f phases
  float* obase = out + (size_t)b * N_STFT * TIME + t0 + tl;
  for (int f = fg; f < N_STFT; f += 64) {
    obase[(size_t)f * TIME] = s_out[tl][f + (f >> 5)];
  }
}

// ---------------- host-side fb structure (replaces imel_prep) -------------
static unsigned char g_tab[15360];
static bool g_tab_ready = false;

static float host_fbval(double freq, const double* f_pts, int m) {
  const double down = (freq - f_pts[m]) / (f_pts[m + 1] - f_pts[m]);
  const double up = (f_pts[m + 2] - freq) / (f_pts[m + 2] - f_pts[m + 1]);
  double v = down < up ? down : up;
  if (v < 0.0) v = 0.0;
  return (float)v;
}

static void build_tab() {
  double f_pts[130];
  const double m_max = 2595.0 * log10(1.0 + 8000.0 / 700.0);
  for (int i = 0; i < 130; ++i) {
    const double m = (double)i * m_max / 129.0;   // linspace(0, m_max, 130)
    f_pts[i] = 700.0 * (pow(10.0, m / 2595.0) - 1.0);
  }
  int* m0f = (int*)g_tab;
  float* w0a = (float*)(g_tab + 5120);
  float* w1a = (float*)(g_tab + 10240);
  for (int f = 0; f < N_STFT; ++f) {
    const double freq = (double)f * (8000.0 / 1024.0);
    int m0 = 0;                      // all-zero rows (f=0, f=1024) -> 0
    for (int m = 0; m < N_MELS; ++m) {
      if (host_fbval(freq, f_pts, m) != 0.0f) { m0 = m; break; }
    }
    if (m0 > N_MELS - 2) m0 = N_MELS - 2;  // keep (m0, m0+1) in range
    m0f[f] = m0;
    w0a[f] = host_fbval(freq, f_pts, m0);
    w1a[f] = host_fbval(freq, f_pts, m0 + 1);
  }
}

extern "C" void kernel_launch(void* const* d_in, const int* in_sizes, int n_in,
                              void* d_out, int out_size, void* d_ws, size_t ws_size,
                              hipStream_t stream) {
  const float* melspec = (const float*)d_in[0];
  const float* spec_init = (const float*)d_in[1];
  float* out = (float*)d_out;

  if (!g_tab_ready) { build_tab(); g_tab_ready = true; }

  int* m0f = (int*)d_ws;                          // 1025 ints
  float* w0a = (float*)((char*)d_ws + 5120);      // 1025 floats
  float* w1a = (float*)((char*)d_ws + 10240);     // 1025 floats

  hipMemcpyAsync(d_ws, g_tab, sizeof(g_tab), hipMemcpyHostToDevice, stream);
  imel_main<<<dim3(1024), dim3(256), 0, stream>>>(melspec, spec_init, m0f, w0a, w1a, out);
}